// Round 1
// 464.650 us; speedup vs baseline: 1.1447x; 1.1447x over previous
//
#include <hip/hip_runtime.h>
#include <stdint.h>

#define NN 8192
#define CC 128
#define BN_EPS 1e-5f

__device__ inline unsigned short f2bf(float f) {
    unsigned int u = __float_as_uint(f);
    unsigned int r = (u + 0x7fffu + ((u >> 16) & 1u)) >> 16;   // RNE
    return (unsigned short)r;
}
__device__ inline float bf2f(unsigned short s) {
    return __uint_as_float(((unsigned int)s) << 16);
}

// ---------------------------------------------------------------------------
// Kernel 1a: compress binary A into a bit-transposed mask + degrees.
//   Mt[band * 8192 + i] : u64 word, bit b set iff A[band*64 + b][i] != 0
//   deg[j]              : rowsum of A[j,:] (float), via ballots
// One wave per 64x256 tile (128 bands x 32 col-tiles = 4096 waves).
// Lane l's float4 covers cols i0+4l..i0+4l+3, so after the 64-row loop each
// lane holds exactly the 4 consecutive mask words it stores (dense 2x16B).
// Pure stream: 268 MB read, 8 MB written, ~25 VALU cyc per 1 KB.
// ---------------------------------------------------------------------------
__global__ __launch_bounds__(256) void k1a_mask(
        const float* __restrict__ A, unsigned long long* __restrict__ Mt,
        float* __restrict__ deg) {
    const int lane = threadIdx.x & 63;
    const int task = blockIdx.x * 4 + (threadIdx.x >> 6);   // 0..4095
    const int band = task >> 5;                             // 0..127
    const int i0   = (task & 31) << 8;                      // col tile * 256
    const int j0   = band << 6;                             // row band * 64

    const float4* Ap = reinterpret_cast<const float4*>(A + (size_t)j0 * NN + i0) + lane;
    unsigned long long m0 = 0, m1 = 0, m2 = 0, m3 = 0;
    int degc = 0;

    #pragma unroll 8
    for (int j = 0; j < 64; ++j) {
        float4 v = Ap[(size_t)j * (NN / 4)];
        bool n0 = v.x != 0.0f, n1 = v.y != 0.0f, n2 = v.z != 0.0f, n3 = v.w != 0.0f;
        unsigned long long b0 = __ballot(n0), b1 = __ballot(n1);
        unsigned long long b2 = __ballot(n2), b3 = __ballot(n3);
        const unsigned long long bit = 1ull << j;
        if (n0) m0 |= bit;
        if (n1) m1 |= bit;
        if (n2) m2 |= bit;
        if (n3) m3 |= bit;
        int cnt = __popcll(b0) + __popcll(b1) + __popcll(b2) + __popcll(b3);
        if (lane == j) degc = cnt;          // lane l owns row j0+l's count
    }

    atomicAdd(&deg[j0 + lane], (float)degc);    // 32 col-tile waves per row
    unsigned long long* p = Mt + (size_t)band * NN + i0 + 4 * lane;
    reinterpret_cast<ulonglong2*>(p)[0] = make_ulonglong2(m0, m1);
    reinterpret_cast<ulonglong2*>(p)[1] = make_ulonglong2(m2, m3);
}

// ---------------------------------------------------------------------------
// Kernel 1c: aggN[i,:] = (1/deg[i]) * sum_{j : A[j,i]!=0} X[j,:]
// One wave per output row i (8192 waves, no LDS, no atomics, full occupancy).
// Lane l loads mask words for bands 2l and 2l+1 (bit b of word 2l+h is input
// row j = l*128 + h*64 + b). Uniform bit-decode loop; X rows (512 B,
// L2-resident) gathered coalesced; accumulate in 2 VGPRs per lane.
// ---------------------------------------------------------------------------
__global__ __launch_bounds__(256) void k1c_gather(
        const unsigned long long* __restrict__ Mt, const float* __restrict__ X,
        const float* __restrict__ deg, float* __restrict__ aggN) {
    const int lane = threadIdx.x & 63;
    const int i = blockIdx.x * 4 + (threadIdx.x >> 6);

    unsigned long long w0 = Mt[(size_t)(2 * lane) * NN + i];
    unsigned long long w1 = Mt[(size_t)(2 * lane + 1) * NN + i];
    float acc0 = 0.0f, acc1 = 0.0f;

    unsigned long long any = __ballot((w0 | w1) != 0ull);
    while (any) {
        int q = __builtin_ctzll(any); any &= any - 1;
        unsigned long long u0 = __shfl(w0, q);
        unsigned long long u1 = __shfl(w1, q);
        const float* Xq = X + (size_t)q * 128 * CC;
        while (u0) {
            int b = __builtin_ctzll(u0); u0 &= u0 - 1;
            const float* xr = Xq + b * CC;
            acc0 += xr[lane];
            acc1 += xr[64 + lane];
        }
        while (u1) {
            int b = __builtin_ctzll(u1); u1 &= u1 - 1;
            const float* xr = Xq + (b + 64) * CC;
            acc0 += xr[lane];
            acc1 += xr[64 + lane];
        }
    }

    float d  = deg[i];
    float rd = (d == 0.0f) ? 1.0f : (1.0f / d);
    aggN[(size_t)i * CC + lane]      = acc0 * rd;
    aggN[(size_t)i * CC + 64 + lane] = acc1 * rd;
}

// ---------------------------------------------------------------------------
// Kernel 2: h = aggN @ Wn^T + X @ Wc^T + bn + bc, fused BN partial sums.
// c = tid&127 (conflict-free LDS W reads), 8 rows/thread, ping-pong k-chunk
// prefetch. W transposed in LDS as bf16 (64 KB). (deg division moved to k1c.)
// ---------------------------------------------------------------------------
__global__ __launch_bounds__(256, 2) void k2_gemm(
        const float* __restrict__ aggN, const float* __restrict__ X,
        const float* __restrict__ Wn, const float* __restrict__ bn,
        const float* __restrict__ Wc, const float* __restrict__ bc,
        float* __restrict__ h, float* __restrict__ bsum, float* __restrict__ bsq) {
    __shared__ unsigned short WtN[128 * 128];   // WtN[k*128+c] = bf16(Wn[c,k])
    __shared__ unsigned short WtC[128 * 128];
    const int tid = threadIdx.x;
    for (int idx = tid * 4; idx < 128 * 128; idx += 1024) {
        float4 wn4 = *reinterpret_cast<const float4*>(Wn + idx);
        float4 wc4 = *reinterpret_cast<const float4*>(Wc + idx);
        int c = idx >> 7, k0 = idx & 127;       // 4 consecutive k, same c
        WtN[(k0 + 0) * 128 + c] = f2bf(wn4.x);
        WtN[(k0 + 1) * 128 + c] = f2bf(wn4.y);
        WtN[(k0 + 2) * 128 + c] = f2bf(wn4.z);
        WtN[(k0 + 3) * 128 + c] = f2bf(wn4.w);
        WtC[(k0 + 0) * 128 + c] = f2bf(wc4.x);
        WtC[(k0 + 1) * 128 + c] = f2bf(wc4.y);
        WtC[(k0 + 2) * 128 + c] = f2bf(wc4.z);
        WtC[(k0 + 3) * 128 + c] = f2bf(wc4.w);
    }
    __syncthreads();
    const int c  = tid & 127;
    const int rg = tid >> 7;
    const int i0 = blockIdx.x * 16 + rg * 8;

    float accN[8], accC[8];
    #pragma unroll
    for (int r = 0; r < 8; ++r) { accN[r] = 0.0f; accC[r] = 0.0f; }

    float4 ar[8], xr[8], an[8], xn[8];

#define LOADK(ab_, xb_, k_) do {                                               \
    _Pragma("unroll")                                                          \
    for (int r = 0; r < 8; ++r) {                                              \
        ab_[r] = *reinterpret_cast<const float4*>(&aggN[(size_t)(i0 + r) * CC + (k_)]); \
        xb_[r] = *reinterpret_cast<const float4*>(&X[(size_t)(i0 + r) * CC + (k_)]);    \
    }                                                                          \
} while (0)

#define COMPK(ab_, xb_, k_) do {                                               \
    _Pragma("unroll")                                                          \
    for (int kk = 0; kk < 4; ++kk) {                                           \
        float wn_ = bf2f(WtN[((k_) + kk) * 128 + c]);                          \
        float wc_ = bf2f(WtC[((k_) + kk) * 128 + c]);                          \
        _Pragma("unroll")                                                      \
        for (int r = 0; r < 8; ++r) {                                          \
            accN[r] = fmaf((&ab_[r].x)[kk], wn_, accN[r]);                     \
            accC[r] = fmaf((&xb_[r].x)[kk], wc_, accC[r]);                     \
        }                                                                      \
    }                                                                          \
} while (0)

    LOADK(ar, xr, 0);
    for (int k = 0; k < 128; k += 8) {
        LOADK(an, xn, k + 4);
        COMPK(ar, xr, k);
        if (k + 8 < 128) LOADK(ar, xr, k + 8);
        COMPK(an, xn, k + 4);
    }

    const float bnc = bn[c], bcc = bc[c];
    float sp = 0.0f, sq = 0.0f;
    #pragma unroll
    for (int r = 0; r < 8; ++r) {
        float hv = accN[r] + accC[r] + bnc + bcc;
        h[(size_t)(i0 + r) * CC + c] = hv;
        sp += hv; sq += hv * hv;
    }
    __syncthreads();                              // WtN reads done; reuse as fp32 scratch
    float* red = reinterpret_cast<float*>(WtN);
    red[rg * 128 + c]       = sp;
    red[256 + rg * 128 + c] = sq;
    __syncthreads();
    if (rg == 0) {
        atomicAdd(&bsum[c], red[c] + red[128 + c]);
        atomicAdd(&bsq[c],  red[256 + c] + red[384 + c]);
    }
}

// ---------------------------------------------------------------------------
// Kernel 3: out = relu(gamma * (h - mu) * rsqrt(var + eps) + beta), float4.
// ---------------------------------------------------------------------------
__global__ __launch_bounds__(256) void k4_bn(
        const float* __restrict__ h, const float* __restrict__ bsum,
        const float* __restrict__ bsq, const float* __restrict__ gamma,
        const float* __restrict__ beta, float* __restrict__ out) {
    const int idx = (blockIdx.x * 256 + threadIdx.x) * 4;
    const int c0  = idx & 127;
    float4 hv = *reinterpret_cast<const float4*>(h + idx);
    float4 s4 = *reinterpret_cast<const float4*>(bsum + c0);
    float4 q4 = *reinterpret_cast<const float4*>(bsq + c0);
    float4 g4 = *reinterpret_cast<const float4*>(gamma + c0);
    float4 b4 = *reinterpret_cast<const float4*>(beta + c0);
    const float invN = 1.0f / 8192.0f;
    float4 o;
    const float* hp = &hv.x; const float* sp = &s4.x; const float* qp = &q4.x;
    const float* gp = &g4.x; const float* bp = &b4.x; float* op = &o.x;
    #pragma unroll
    for (int jj = 0; jj < 4; ++jj) {
        float mu  = sp[jj] * invN;
        float var = qp[jj] * invN - mu * mu;
        float sc  = gp[jj] * rsqrtf(var + BN_EPS);
        float v   = (hp[jj] - mu) * sc + bp[jj];
        op[jj] = v > 0.0f ? v : 0.0f;
    }
    *reinterpret_cast<float4*>(out + idx) = o;
}

extern "C" void kernel_launch(void* const* d_in, const int* in_sizes, int n_in,
                              void* d_out, int out_size, void* d_ws, size_t ws_size,
                              hipStream_t stream) {
    const float* X     = (const float*)d_in[0];   // [8192,128]
    const float* A     = (const float*)d_in[1];   // [8192,8192]
    const float* Wn    = (const float*)d_in[2];   // [128,128]
    const float* bn    = (const float*)d_in[3];
    const float* Wc    = (const float*)d_in[4];
    const float* bc    = (const float*)d_in[5];
    const float* gamma = (const float*)d_in[6];
    const float* beta  = (const float*)d_in[7];
    float* out = (float*)d_out;

    // Workspace layout (12.65 MB):
    //   deg   @ 0        (32 KB, zeroed)
    //   bsum  @ 32768    (512 B, zeroed)
    //   bsq   @ 33280    (512 B, zeroed)
    //   aggN  @ 65536    (4 MB, fully written by k1c)
    //   Mt    @ 4259840  (8 MB, fully written by k1a)
    //   h     aliases Mt (Mt dead after k1c; k2 writes h before k4 reads)
    char* ws = (char*)d_ws;
    float* deg  = (float*)(ws);
    float* bsum = (float*)(ws + 32768);
    float* bsq  = (float*)(ws + 33280);
    float* aggN = (float*)(ws + 65536);
    unsigned long long* Mt = (unsigned long long*)(ws + 4259840);
    float* h    = (float*)(ws + 4259840);

    hipMemsetAsync(d_ws, 0, 33792, stream);

    k1a_mask  <<<1024, 256, 0, stream>>>(A, Mt, deg);
    k1c_gather<<<2048, 256, 0, stream>>>(Mt, X, deg, aggN);
    k2_gemm   <<<512,  256, 0, stream>>>(aggN, X, Wn, bn, Wc, bc, h, bsum, bsq);
    k4_bn     <<<1024, 256, 0, stream>>>(h, bsum, bsq, gamma, beta, out);
}

// Round 2
// 459.720 us; speedup vs baseline: 1.1570x; 1.0107x over previous
//
#include <hip/hip_runtime.h>
#include <stdint.h>

#define NN 8192
#define CC 128
#define BN_EPS 1e-5f

__device__ inline unsigned short f2bf(float f) {
    unsigned int u = __float_as_uint(f);
    unsigned int r = (u + 0x7fffu + ((u >> 16) & 1u)) >> 16;   // RNE
    return (unsigned short)r;
}
__device__ inline float bf2f(unsigned short s) {
    return __uint_as_float(((unsigned int)s) << 16);
}

// ---------------------------------------------------------------------------
// Kernel 1a: compress binary A into a bit-transposed mask + degrees.
//   Mt[band * 8192 + i] : u64 word, bit b set iff A[band*64 + b][i] != 0
//   deg[j]              : rowsum of A[j,:] (float)
// One wave per 64x128 tile (128 bands x 64 col-tiles = 8192 waves -> 8/SIMD).
// Lane l's uint2 covers cols i0+2l..i0+2l+1; after the 64-row loop each lane
// holds the 2 consecutive mask words it stores (dense 16B/lane).
// deg: per-lane popcount of ballots, block-level LDS reduce, 16 atomics/row.
// ---------------------------------------------------------------------------
__global__ __launch_bounds__(256, 8) void k1a_mask(
        const float* __restrict__ A, unsigned long long* __restrict__ Mt,
        float* __restrict__ deg) {
    __shared__ float dred[4][64];
    const int lane = threadIdx.x & 63;
    const int wave = threadIdx.x >> 6;
    const int task = blockIdx.x * 4 + wave;     // 0..8191
    const int band = task >> 6;                 // 0..127
    const int i0   = (task & 63) << 7;          // col tile * 128
    const int j0   = band << 6;                 // row band * 64

    const uint2* Ap = reinterpret_cast<const uint2*>(A + (size_t)j0 * NN + i0) + lane;
    unsigned long long m0 = 0, m1 = 0;
    float degc = 0.0f;

    #pragma unroll 8
    for (int j = 0; j < 64; ++j) {
        uint2 v = Ap[(size_t)j * (NN / 2)];     // 0.0f or 1.0f -> bit test
        bool n0 = v.x != 0u, n1 = v.y != 0u;
        unsigned long long b0 = __ballot(n0), b1 = __ballot(n1);
        const unsigned long long bit = 1ull << j;
        if (n0) m0 |= bit;
        if (n1) m1 |= bit;
        if (lane == j) degc = (float)(__popcll(b0) + __popcll(b1));
    }

    unsigned long long* p = Mt + (size_t)band * NN + i0 + 2 * lane;
    *reinterpret_cast<ulonglong2*>(p) = make_ulonglong2(m0, m1);

    dred[wave][lane] = degc;
    __syncthreads();
    if (wave == 0) {
        float s = dred[0][lane] + dred[1][lane] + dred[2][lane] + dred[3][lane];
        atomicAdd(&deg[j0 + lane], s);
    }
}

// ---------------------------------------------------------------------------
// Kernel 1c: aggN[i,:] = (1/deg[i]) * sum_{j : A[j,i]!=0} X[j,:]
// One BLOCK per output row i; 4 waves split the 128 mask words (32 each) so
// the serial decode/gather chain per wave is ~8 neighbors, then LDS reduce.
// Lane l<32 of wave w holds word band=w*32+l (bit b -> input row band*64+b).
// X rows (512 B, L2-resident) gathered coalesced; acc in 2 VGPRs per lane.
// ---------------------------------------------------------------------------
__global__ __launch_bounds__(256, 8) void k1c_gather(
        const unsigned long long* __restrict__ Mt, const float* __restrict__ X,
        const float* __restrict__ deg, float* __restrict__ aggN) {
    __shared__ float red[4][128];
    const int lane = threadIdx.x & 63;
    const int wave = threadIdx.x >> 6;
    const int i = blockIdx.x;

    unsigned long long w = 0;
    if (lane < 32)
        w = Mt[(size_t)(wave * 32 + lane) * NN + i];
    float acc0 = 0.0f, acc1 = 0.0f;

    unsigned long long any = __ballot(w != 0ull);   // bits only in lanes 0..31
    while (any) {
        int q = __builtin_ctzll(any); any &= any - 1;
        unsigned long long u = __shfl(w, q);
        const float* Xq = X + (size_t)((wave * 32 + q) * 64) * CC;
        while (u) {
            int b = __builtin_ctzll(u); u &= u - 1;
            const float* xr = Xq + b * CC;
            acc0 += xr[lane];
            acc1 += xr[64 + lane];
        }
    }

    red[wave][lane]      = acc0;
    red[wave][64 + lane] = acc1;
    __syncthreads();
    if (wave == 0) {
        float s0 = red[0][lane]      + red[1][lane]      + red[2][lane]      + red[3][lane];
        float s1 = red[0][64 + lane] + red[1][64 + lane] + red[2][64 + lane] + red[3][64 + lane];
        float d  = deg[i];
        float rd = (d == 0.0f) ? 1.0f : (1.0f / d);
        aggN[(size_t)i * CC + lane]      = s0 * rd;
        aggN[(size_t)i * CC + 64 + lane] = s1 * rd;
    }
}

// ---------------------------------------------------------------------------
// Kernel 2: h = aggN @ Wn^T + X @ Wc^T + bn + bc, fused BN partial sums.
// c = tid&127 (conflict-free LDS W reads), 8 rows/thread, ping-pong k-chunk
// prefetch. W transposed in LDS as bf16 (64 KB).
// ---------------------------------------------------------------------------
__global__ __launch_bounds__(256, 2) void k2_gemm(
        const float* __restrict__ aggN, const float* __restrict__ X,
        const float* __restrict__ Wn, const float* __restrict__ bn,
        const float* __restrict__ Wc, const float* __restrict__ bc,
        float* __restrict__ h, float* __restrict__ bsum, float* __restrict__ bsq) {
    __shared__ unsigned short WtN[128 * 128];   // WtN[k*128+c] = bf16(Wn[c,k])
    __shared__ unsigned short WtC[128 * 128];
    const int tid = threadIdx.x;
    for (int idx = tid * 4; idx < 128 * 128; idx += 1024) {
        float4 wn4 = *reinterpret_cast<const float4*>(Wn + idx);
        float4 wc4 = *reinterpret_cast<const float4*>(Wc + idx);
        int c = idx >> 7, k0 = idx & 127;       // 4 consecutive k, same c
        WtN[(k0 + 0) * 128 + c] = f2bf(wn4.x);
        WtN[(k0 + 1) * 128 + c] = f2bf(wn4.y);
        WtN[(k0 + 2) * 128 + c] = f2bf(wn4.z);
        WtN[(k0 + 3) * 128 + c] = f2bf(wn4.w);
        WtC[(k0 + 0) * 128 + c] = f2bf(wc4.x);
        WtC[(k0 + 1) * 128 + c] = f2bf(wc4.y);
        WtC[(k0 + 2) * 128 + c] = f2bf(wc4.z);
        WtC[(k0 + 3) * 128 + c] = f2bf(wc4.w);
    }
    __syncthreads();
    const int c  = tid & 127;
    const int rg = tid >> 7;
    const int i0 = blockIdx.x * 16 + rg * 8;

    float accN[8], accC[8];
    #pragma unroll
    for (int r = 0; r < 8; ++r) { accN[r] = 0.0f; accC[r] = 0.0f; }

    float4 ar[8], xr[8], an[8], xn[8];

#define LOADK(ab_, xb_, k_) do {                                               \
    _Pragma("unroll")                                                          \
    for (int r = 0; r < 8; ++r) {                                              \
        ab_[r] = *reinterpret_cast<const float4*>(&aggN[(size_t)(i0 + r) * CC + (k_)]); \
        xb_[r] = *reinterpret_cast<const float4*>(&X[(size_t)(i0 + r) * CC + (k_)]);    \
    }                                                                          \
} while (0)

#define COMPK(ab_, xb_, k_) do {                                               \
    _Pragma("unroll")                                                          \
    for (int kk = 0; kk < 4; ++kk) {                                           \
        float wn_ = bf2f(WtN[((k_) + kk) * 128 + c]);                          \
        float wc_ = bf2f(WtC[((k_) + kk) * 128 + c]);                          \
        _Pragma("unroll")                                                      \
        for (int r = 0; r < 8; ++r) {                                          \
            accN[r] = fmaf((&ab_[r].x)[kk], wn_, accN[r]);                     \
            accC[r] = fmaf((&xb_[r].x)[kk], wc_, accC[r]);                     \
        }                                                                      \
    }                                                                          \
} while (0)

    LOADK(ar, xr, 0);
    for (int k = 0; k < 128; k += 8) {
        LOADK(an, xn, k + 4);
        COMPK(ar, xr, k);
        if (k + 8 < 128) LOADK(ar, xr, k + 8);
        COMPK(an, xn, k + 4);
    }

    const float bnc = bn[c], bcc = bc[c];
    float sp = 0.0f, sq = 0.0f;
    #pragma unroll
    for (int r = 0; r < 8; ++r) {
        float hv = accN[r] + accC[r] + bnc + bcc;
        h[(size_t)(i0 + r) * CC + c] = hv;
        sp += hv; sq += hv * hv;
    }
    __syncthreads();                              // WtN reads done; reuse as fp32 scratch
    float* red = reinterpret_cast<float*>(WtN);
    red[rg * 128 + c]       = sp;
    red[256 + rg * 128 + c] = sq;
    __syncthreads();
    if (rg == 0) {
        atomicAdd(&bsum[c], red[c] + red[128 + c]);
        atomicAdd(&bsq[c],  red[256 + c] + red[384 + c]);
    }
}

// ---------------------------------------------------------------------------
// Kernel 3: out = relu(gamma * (h - mu) * rsqrt(var + eps) + beta), float4.
// ---------------------------------------------------------------------------
__global__ __launch_bounds__(256) void k4_bn(
        const float* __restrict__ h, const float* __restrict__ bsum,
        const float* __restrict__ bsq, const float* __restrict__ gamma,
        const float* __restrict__ beta, float* __restrict__ out) {
    const int idx = (blockIdx.x * 256 + threadIdx.x) * 4;
    const int c0  = idx & 127;
    float4 hv = *reinterpret_cast<const float4*>(h + idx);
    float4 s4 = *reinterpret_cast<const float4*>(bsum + c0);
    float4 q4 = *reinterpret_cast<const float4*>(bsq + c0);
    float4 g4 = *reinterpret_cast<const float4*>(gamma + c0);
    float4 b4 = *reinterpret_cast<const float4*>(beta + c0);
    const float invN = 1.0f / 8192.0f;
    float4 o;
    const float* hp = &hv.x; const float* sp = &s4.x; const float* qp = &q4.x;
    const float* gp = &g4.x; const float* bp = &b4.x; float* op = &o.x;
    #pragma unroll
    for (int jj = 0; jj < 4; ++jj) {
        float mu  = sp[jj] * invN;
        float var = qp[jj] * invN - mu * mu;
        float sc  = gp[jj] * rsqrtf(var + BN_EPS);
        float v   = (hp[jj] - mu) * sc + bp[jj];
        op[jj] = v > 0.0f ? v : 0.0f;
    }
    *reinterpret_cast<float4*>(out + idx) = o;
}

extern "C" void kernel_launch(void* const* d_in, const int* in_sizes, int n_in,
                              void* d_out, int out_size, void* d_ws, size_t ws_size,
                              hipStream_t stream) {
    const float* X     = (const float*)d_in[0];   // [8192,128]
    const float* A     = (const float*)d_in[1];   // [8192,8192]
    const float* Wn    = (const float*)d_in[2];   // [128,128]
    const float* bn    = (const float*)d_in[3];
    const float* Wc    = (const float*)d_in[4];
    const float* bc    = (const float*)d_in[5];
    const float* gamma = (const float*)d_in[6];
    const float* beta  = (const float*)d_in[7];
    float* out = (float*)d_out;

    // Workspace layout (12.65 MB):
    //   deg   @ 0        (32 KB, zeroed)
    //   bsum  @ 32768    (512 B, zeroed)
    //   bsq   @ 33280    (512 B, zeroed)
    //   aggN  @ 65536    (4 MB, fully written by k1c)
    //   Mt    @ 4259840  (8 MB, fully written by k1a)
    //   h     aliases Mt (Mt dead after k1c; k2 writes h before k4 reads)
    char* ws = (char*)d_ws;
    float* deg  = (float*)(ws);
    float* bsum = (float*)(ws + 32768);
    float* bsq  = (float*)(ws + 33280);
    float* aggN = (float*)(ws + 65536);
    unsigned long long* Mt = (unsigned long long*)(ws + 4259840);
    float* h    = (float*)(ws + 4259840);

    hipMemsetAsync(d_ws, 0, 33792, stream);

    k1a_mask  <<<2048, 256, 0, stream>>>(A, Mt, deg);
    k1c_gather<<<8192, 256, 0, stream>>>(Mt, X, deg, aggN);
    k2_gemm   <<<512,  256, 0, stream>>>(aggN, X, Wn, bn, Wc, bc, h, bsum, bsq);
    k4_bn     <<<1024, 256, 0, stream>>>(h, bsum, bsq, gamma, beta, out);
}

// Round 3
// 446.044 us; speedup vs baseline: 1.1924x; 1.0307x over previous
//
#include <hip/hip_runtime.h>
#include <stdint.h>

#define NN 8192
#define CC 128
#define BN_EPS 1e-5f

__device__ inline unsigned short f2bf(float f) {
    unsigned int u = __float_as_uint(f);
    unsigned int r = (u + 0x7fffu + ((u >> 16) & 1u)) >> 16;   // RNE
    return (unsigned short)r;
}

// ---------------------------------------------------------------------------
// Kernel 1a: compress binary A into a bit-transposed mask + degrees.
//   Mt[band * 8192 + i] : u64 word, bit b set iff A[band*64 + b][i] != 0
//   deg[j]              : rowsum of A[j,:] (float)
// One wave per 64x128 tile (128 bands x 64 col-tiles = 8192 waves -> 8/SIMD).
// (unchanged from prev round — width/occupancy shown insensitive)
// ---------------------------------------------------------------------------
__global__ __launch_bounds__(256, 8) void k1a_mask(
        const float* __restrict__ A, unsigned long long* __restrict__ Mt,
        float* __restrict__ deg) {
    __shared__ float dred[4][64];
    const int lane = threadIdx.x & 63;
    const int wave = threadIdx.x >> 6;
    const int task = blockIdx.x * 4 + wave;     // 0..8191
    const int band = task >> 6;                 // 0..127
    const int i0   = (task & 63) << 7;          // col tile * 128
    const int j0   = band << 6;                 // row band * 64

    const uint2* Ap = reinterpret_cast<const uint2*>(A + (size_t)j0 * NN + i0) + lane;
    unsigned long long m0 = 0, m1 = 0;
    float degc = 0.0f;

    #pragma unroll 8
    for (int j = 0; j < 64; ++j) {
        uint2 v = Ap[(size_t)j * (NN / 2)];     // 0.0f or 1.0f -> bit test
        bool n0 = v.x != 0u, n1 = v.y != 0u;
        unsigned long long b0 = __ballot(n0), b1 = __ballot(n1);
        const unsigned long long bit = 1ull << j;
        if (n0) m0 |= bit;
        if (n1) m1 |= bit;
        if (lane == j) degc = (float)(__popcll(b0) + __popcll(b1));
    }

    unsigned long long* p = Mt + (size_t)band * NN + i0 + 2 * lane;
    *reinterpret_cast<ulonglong2*>(p) = make_ulonglong2(m0, m1);

    dred[wave][lane] = degc;
    __syncthreads();
    if (wave == 0) {
        float s = dred[0][lane] + dred[1][lane] + dred[2][lane] + dred[3][lane];
        atomicAdd(&deg[j0 + lane], s);
    }
}

// ---------------------------------------------------------------------------
// Kernel 1c: aggN[i,:] = (1/deg[i]) * sum_{j : A[j,i]!=0} X[j,:]
// One BLOCK per output row i; 4 waves split the 128 mask words, LDS reduce.
// (unchanged from prev round)
// ---------------------------------------------------------------------------
__global__ __launch_bounds__(256, 8) void k1c_gather(
        const unsigned long long* __restrict__ Mt, const float* __restrict__ X,
        const float* __restrict__ deg, float* __restrict__ aggN) {
    __shared__ float red[4][128];
    const int lane = threadIdx.x & 63;
    const int wave = threadIdx.x >> 6;
    const int i = blockIdx.x;

    unsigned long long w = 0;
    if (lane < 32)
        w = Mt[(size_t)(wave * 32 + lane) * NN + i];
    float acc0 = 0.0f, acc1 = 0.0f;

    unsigned long long any = __ballot(w != 0ull);   // bits only in lanes 0..31
    while (any) {
        int q = __builtin_ctzll(any); any &= any - 1;
        unsigned long long u = __shfl(w, q);
        const float* Xq = X + (size_t)((wave * 32 + q) * 64) * CC;
        while (u) {
            int b = __builtin_ctzll(u); u &= u - 1;
            const float* xr = Xq + b * CC;
            acc0 += xr[lane];
            acc1 += xr[64 + lane];
        }
    }

    red[wave][lane]      = acc0;
    red[wave][64 + lane] = acc1;
    __syncthreads();
    if (wave == 0) {
        float s0 = red[0][lane]      + red[1][lane]      + red[2][lane]      + red[3][lane];
        float s1 = red[0][64 + lane] + red[1][64 + lane] + red[2][64 + lane] + red[3][64 + lane];
        float d  = deg[i];
        float rd = (d == 0.0f) ? 1.0f : (1.0f / d);
        aggN[(size_t)i * CC + lane]      = s0 * rd;
        aggN[(size_t)i * CC + 64 + lane] = s1 * rd;
    }
}

// ---------------------------------------------------------------------------
// Kernel 2: h = aggN @ Wn^T + X @ Wc^T + bn + bc, fused BN partial sums.
// NEW staging: single fused LDS array Wp[swz(k*128+c)] = bf16(Wn)|bf16(Wc)<<16
// with XOR swizzle ^(k&31):
//   - main-loop reads: lanes have consecutive c -> (c^const) permutation ->
//     2 lanes/bank (free), ONE ds_read_b32 per (k, both weights).
//   - staging writes: was 32-way conflict on every ds_write_u16 (all 64 lanes
//     hit bank 0: addr stride 1024B); now <=4-8-way on half the instructions.
// Unpack: wn = pk<<16 (bf16 low half), wc = pk & 0xffff0000.
// ---------------------------------------------------------------------------
__global__ __launch_bounds__(256, 2) void k2_gemm(
        const float* __restrict__ aggN, const float* __restrict__ X,
        const float* __restrict__ Wn, const float* __restrict__ bn,
        const float* __restrict__ Wc, const float* __restrict__ bc,
        float* __restrict__ h, float* __restrict__ bsum, float* __restrict__ bsq) {
    __shared__ unsigned int Wp[128 * 128];      // 64 KB -> 2 blocks/CU
    const int tid = threadIdx.x;
    for (int idx = tid * 4; idx < 128 * 128; idx += 1024) {
        float4 wn4 = *reinterpret_cast<const float4*>(Wn + idx);
        float4 wc4 = *reinterpret_cast<const float4*>(Wc + idx);
        int c = idx >> 7, k0 = idx & 127;       // 4 consecutive k, same c
        #pragma unroll
        for (int q = 0; q < 4; ++q) {
            unsigned int pk = (unsigned int)f2bf((&wn4.x)[q])
                            | ((unsigned int)f2bf((&wc4.x)[q]) << 16);
            int k = k0 + q;
            Wp[(k * 128 + c) ^ (k & 31)] = pk;
        }
    }
    __syncthreads();
    const int c  = tid & 127;
    const int rg = tid >> 7;
    const int i0 = blockIdx.x * 16 + rg * 8;

    float accN[8], accC[8];
    #pragma unroll
    for (int r = 0; r < 8; ++r) { accN[r] = 0.0f; accC[r] = 0.0f; }

    float4 ar[8], xr[8], an[8], xn[8];

#define LOADK(ab_, xb_, k_) do {                                               \
    _Pragma("unroll")                                                          \
    for (int r = 0; r < 8; ++r) {                                              \
        ab_[r] = *reinterpret_cast<const float4*>(&aggN[(size_t)(i0 + r) * CC + (k_)]); \
        xb_[r] = *reinterpret_cast<const float4*>(&X[(size_t)(i0 + r) * CC + (k_)]);    \
    }                                                                          \
} while (0)

#define COMPK(ab_, xb_, k_) do {                                               \
    _Pragma("unroll")                                                          \
    for (int kk = 0; kk < 4; ++kk) {                                           \
        int kq_ = (k_) + kk;                                                   \
        unsigned int pk_ = Wp[(kq_ * 128 + c) ^ (kq_ & 31)];                   \
        float wn_ = __uint_as_float(pk_ << 16);                                \
        float wc_ = __uint_as_float(pk_ & 0xffff0000u);                        \
        _Pragma("unroll")                                                      \
        for (int r = 0; r < 8; ++r) {                                          \
            accN[r] = fmaf((&ab_[r].x)[kk], wn_, accN[r]);                     \
            accC[r] = fmaf((&xb_[r].x)[kk], wc_, accC[r]);                     \
        }                                                                      \
    }                                                                          \
} while (0)

    LOADK(ar, xr, 0);
    for (int k = 0; k < 128; k += 8) {
        LOADK(an, xn, k + 4);
        COMPK(ar, xr, k);
        if (k + 8 < 128) LOADK(ar, xr, k + 8);
        COMPK(an, xn, k + 4);
    }

    const float bnc = bn[c], bcc = bc[c];
    float sp = 0.0f, sq = 0.0f;
    #pragma unroll
    for (int r = 0; r < 8; ++r) {
        float hv = accN[r] + accC[r] + bnc + bcc;
        h[(size_t)(i0 + r) * CC + c] = hv;
        sp += hv; sq += hv * hv;
    }
    __syncthreads();                              // Wp reads done; reuse as fp32 scratch
    float* red = reinterpret_cast<float*>(Wp);
    red[rg * 128 + c]       = sp;
    red[256 + rg * 128 + c] = sq;
    __syncthreads();
    if (rg == 0) {
        atomicAdd(&bsum[c], red[c] + red[128 + c]);
        atomicAdd(&bsq[c],  red[256 + c] + red[384 + c]);
    }
}

// ---------------------------------------------------------------------------
// Kernel 3: out = relu(gamma * (h - mu) * rsqrt(var + eps) + beta), float4.
// ---------------------------------------------------------------------------
__global__ __launch_bounds__(256) void k4_bn(
        const float* __restrict__ h, const float* __restrict__ bsum,
        const float* __restrict__ bsq, const float* __restrict__ gamma,
        const float* __restrict__ beta, float* __restrict__ out) {
    const int idx = (blockIdx.x * 256 + threadIdx.x) * 4;
    const int c0  = idx & 127;
    float4 hv = *reinterpret_cast<const float4*>(h + idx);
    float4 s4 = *reinterpret_cast<const float4*>(bsum + c0);
    float4 q4 = *reinterpret_cast<const float4*>(bsq + c0);
    float4 g4 = *reinterpret_cast<const float4*>(gamma + c0);
    float4 b4 = *reinterpret_cast<const float4*>(beta + c0);
    const float invN = 1.0f / 8192.0f;
    float4 o;
    const float* hp = &hv.x; const float* sp = &s4.x; const float* qp = &q4.x;
    const float* gp = &g4.x; const float* bp = &b4.x; float* op = &o.x;
    #pragma unroll
    for (int jj = 0; jj < 4; ++jj) {
        float mu  = sp[jj] * invN;
        float var = qp[jj] * invN - mu * mu;
        float sc  = gp[jj] * rsqrtf(var + BN_EPS);
        float v   = (hp[jj] - mu) * sc + bp[jj];
        op[jj] = v > 0.0f ? v : 0.0f;
    }
    *reinterpret_cast<float4*>(out + idx) = o;
}

extern "C" void kernel_launch(void* const* d_in, const int* in_sizes, int n_in,
                              void* d_out, int out_size, void* d_ws, size_t ws_size,
                              hipStream_t stream) {
    const float* X     = (const float*)d_in[0];   // [8192,128]
    const float* A     = (const float*)d_in[1];   // [8192,8192]
    const float* Wn    = (const float*)d_in[2];   // [128,128]
    const float* bn    = (const float*)d_in[3];
    const float* Wc    = (const float*)d_in[4];
    const float* bc    = (const float*)d_in[5];
    const float* gamma = (const float*)d_in[6];
    const float* beta  = (const float*)d_in[7];
    float* out = (float*)d_out;

    // Workspace layout (12.65 MB):
    //   deg   @ 0        (32 KB, zeroed)
    //   bsum  @ 32768    (512 B, zeroed)
    //   bsq   @ 33280    (512 B, zeroed)
    //   aggN  @ 65536    (4 MB, fully written by k1c)
    //   Mt    @ 4259840  (8 MB, fully written by k1a)
    //   h     aliases Mt (Mt dead after k1c; k2 writes h before k4 reads)
    char* ws = (char*)d_ws;
    float* deg  = (float*)(ws);
    float* bsum = (float*)(ws + 32768);
    float* bsq  = (float*)(ws + 33280);
    float* aggN = (float*)(ws + 65536);
    unsigned long long* Mt = (unsigned long long*)(ws + 4259840);
    float* h    = (float*)(ws + 4259840);

    hipMemsetAsync(d_ws, 0, 33792, stream);

    k1a_mask  <<<2048, 256, 0, stream>>>(A, Mt, deg);
    k1c_gather<<<8192, 256, 0, stream>>>(Mt, X, deg, aggN);
    k2_gemm   <<<512,  256, 0, stream>>>(aggN, X, Wn, bn, Wc, bc, h, bsum, bsq);
    k4_bn     <<<1024, 256, 0, stream>>>(h, bsum, bsq, gamma, beta, out);
}